// Round 7
// baseline (1480.509 us; speedup 1.0000x reference)
//
#include <hip/hip_runtime.h>
#include <math.h>

#define B_ 512
#define N_ 101
#define H_ 128
#define T_ 140
#define M37 0x1FFFFFFFFFull

// lgkm-only barrier: does NOT drain vmcnt (global prefetches stay in flight)
#define BAR() asm volatile("s_waitcnt lgkmcnt(0)\n\ts_barrier" ::: "memory")

// ---------------- DPP wave64 reductions ----------------
template <int CTRL, int RM>
__device__ __forceinline__ float dpp_max_step(float x) {
  int t = __builtin_amdgcn_update_dpp((int)0xFF800000, __float_as_int(x), CTRL, RM, 0xF, false);
  return fmaxf(x, __int_as_float(t));
}
template <int CTRL, int RM>
__device__ __forceinline__ float dpp_add_step(float x) {
  int t = __builtin_amdgcn_update_dpp(0, __float_as_int(x), CTRL, RM, 0xF, false);
  return x + __int_as_float(t);
}
__device__ __forceinline__ float wave_max64(float x) {
  x = dpp_max_step<0x111, 0xF>(x);
  x = dpp_max_step<0x112, 0xF>(x);
  x = dpp_max_step<0x114, 0xF>(x);
  x = dpp_max_step<0x118, 0xF>(x);
  x = dpp_max_step<0x142, 0xA>(x);
  x = dpp_max_step<0x143, 0xC>(x);
  return __int_as_float(__builtin_amdgcn_readlane(__float_as_int(x), 63));
}
__device__ __forceinline__ float wave_sum64(float x) {
  x = dpp_add_step<0x111, 0xF>(x);
  x = dpp_add_step<0x112, 0xF>(x);
  x = dpp_add_step<0x114, 0xF>(x);
  x = dpp_add_step<0x118, 0xF>(x);
  x = dpp_add_step<0x142, 0xA>(x);
  x = dpp_add_step<0x143, 0xC>(x);
  return __int_as_float(__builtin_amdgcn_readlane(__float_as_int(x), 63));
}

// ---------------- 128x32 GEMM tile (bit-identical to R2's gemm_tile) ----
__device__ __forceinline__ void gemm_tile_dev(
    const float* A, const float* B, float* C, int cb, int transB, int tid)
{
  int cc = cb * 32 + (tid & 7) * 4;
  int r0 = tid >> 3;
  float4 acc0 = {0,0,0,0}, acc1 = {0,0,0,0}, acc2 = {0,0,0,0}, acc3 = {0,0,0,0};
  for (int k = 0; k < 128; ++k) {
    float4 b4;
    if (!transB) {
      b4 = *(const float4*)(B + k * 128 + cc);
    } else {
      b4.x = B[(cc + 0) * 128 + k];
      b4.y = B[(cc + 1) * 128 + k];
      b4.z = B[(cc + 2) * 128 + k];
      b4.w = B[(cc + 3) * 128 + k];
    }
    float a0 = A[(r0 +  0) * 128 + k];
    float a1 = A[(r0 + 32) * 128 + k];
    float a2 = A[(r0 + 64) * 128 + k];
    float a3 = A[(r0 + 96) * 128 + k];
    acc0.x += a0 * b4.x; acc0.y += a0 * b4.y; acc0.z += a0 * b4.z; acc0.w += a0 * b4.w;
    acc1.x += a1 * b4.x; acc1.y += a1 * b4.y; acc1.z += a1 * b4.z; acc1.w += a1 * b4.w;
    acc2.x += a2 * b4.x; acc2.y += a2 * b4.y; acc2.z += a2 * b4.z; acc2.w += a2 * b4.w;
    acc3.x += a3 * b4.x; acc3.y += a3 * b4.y; acc3.z += a3 * b4.z; acc3.w += a3 * b4.w;
  }
  *(float4*)(C + (r0 +  0) * 128 + cc) = acc0;
  *(float4*)(C + (r0 + 32) * 128 + cc) = acc1;
  *(float4*)(C + (r0 + 64) * 128 + cc) = acc2;
  *(float4*)(C + (r0 + 96) * 128 + cc) = acc3;
}

// n1: Wfw(4) + Wc(4) + wcap(1) + M^2(4)
__global__ __launch_bounds__(256) void stage_a(
    const float* __restrict__ Wfc, const float* __restrict__ Ww,
    const float* __restrict__ Wpk, const float* __restrict__ Wat,
    const float* __restrict__ F,
    float* __restrict__ Wfw, float* __restrict__ Wc, float* __restrict__ wcap,
    float* __restrict__ Mbuf)
{
  int j = blockIdx.x, tid = threadIdx.x;
  if (j < 4)       gemm_tile_dev(Wfc, Ww, Wfw, j, 0, tid);
  else if (j < 8)  gemm_tile_dev(Wpk, Wat, Wc, j - 4, 1, tid);
  else if (j == 8) {
    if (tid < 128) {
      float s = 0.f;
      for (int k = 0; k < 128; ++k) s += Wfc[128 * 128 + k] * Ww[k * 128 + tid];
      wcap[tid] = s;
    }
  } else gemm_tile_dev(F, F, Mbuf + 2ll * 16384, j - 9, 0, tid);
}

// n2: chain L=2 (M^3,M^4 : 8 tiles) + encW (1616 tiles)
__global__ __launch_bounds__(256) void stage_b(
    const float* __restrict__ F, const float* __restrict__ enc,
    const float* __restrict__ Wfw, float* __restrict__ Mbuf,
    float* __restrict__ encW)
{
  int bx = blockIdx.x, tid = threadIdx.x;
  if (bx < 8) {
    int s = (bx >> 2) + 1, cb = bx & 3;
    const float* As = (s == 1) ? F : Mbuf + (long long)s * 16384;
    gemm_tile_dev(As, Mbuf + 2ll * 16384, Mbuf + (long long)(2 + s) * 16384, cb, 0, tid);
  } else {
    int jj = bx - 8, rb = jj >> 2, cb = jj & 3;
    gemm_tile_dev(enc + (long long)rb * 16384, Wfw, encW + (long long)rb * 16384, cb, 0, tid);
  }
}

// n3..n7: chain level L: M^{L+s} = M^s @ M^L, s=1..c (grid = 4c)
__global__ __launch_bounds__(256) void chainL(
    const float* __restrict__ F, float* __restrict__ Mbuf, int L)
{
  int bx = blockIdx.x, tid = threadIdx.x;
  int s = (bx >> 2) + 1, cb = bx & 3;
  const float* As = (s == 1) ? F : Mbuf + (long long)s * 16384;
  gemm_tile_dev(As, Mbuf + (long long)L * 16384, Mbuf + (long long)(L + s) * 16384, cb, 0, tid);
}

// n8: chain L=128 (48 tiles) + A_t for t=0..126 (508 tiles)
__global__ __launch_bounds__(256) void stage_n8(
    const float* __restrict__ F, const float* __restrict__ Ww,
    float* __restrict__ Mbuf, float* __restrict__ Abuf)
{
  int bx = blockIdx.x, tid = threadIdx.x;
  if (bx < 48) {
    int s = (bx >> 2) + 1, cb = bx & 3;
    const float* As = (s == 1) ? F : Mbuf + (long long)s * 16384;
    gemm_tile_dev(As, Mbuf + 128ll * 16384, Mbuf + (long long)(128 + s) * 16384, cb, 0, tid);
  } else {
    int jj = bx - 48, t = jj >> 2, cb = jj & 3;
    const float* Ms = (t == 0) ? F : Mbuf + (long long)(t + 1) * 16384;
    gemm_tile_dev(Ms, Ww, Abuf + (long long)t * 16384, cb, 0, tid);
  }
}

// n9: A_t for t=127..139 (52 tiles) + Qpool[t] for t=0..126 (2032 tiles)
__global__ __launch_bounds__(256) void stage_n9(
    const float* __restrict__ Ww, const float* __restrict__ pool,
    float* __restrict__ Mbuf, float* __restrict__ Abuf, float* __restrict__ Qpl)
{
  int bx = blockIdx.x, tid = threadIdx.x;
  if (bx < 52) {
    int t = 127 + (bx >> 2), cb = bx & 3;
    gemm_tile_dev(Mbuf + (long long)(t + 1) * 16384, Ww, Abuf + (long long)t * 16384, cb, 0, tid);
  } else {
    int jj = bx - 52, t = jj >> 4, sub = jj & 15, rb = sub >> 2, cb = sub & 3;
    gemm_tile_dev(pool + (long long)rb * 16384, Abuf + (long long)t * 16384,
                  Qpl + (long long)t * 65536 + (long long)rb * 16384, cb, 0, tid);
  }
}

// n10: Qpool[t] for t=127..139 (208 tiles)
__global__ __launch_bounds__(256) void stage_n10(
    const float* __restrict__ pool, float* __restrict__ Abuf, float* __restrict__ Qpl)
{
  int bx = blockIdx.x, tid = threadIdx.x;
  int t = 127 + (bx >> 4), sub = bx & 15, rb = sub >> 2, cb = sub & 3;
  gemm_tile_dev(pool + (long long)rb * 16384, Abuf + (long long)t * 16384,
                Qpl + (long long)t * 65536 + (long long)rb * 16384, cb, 0, tid);
}

// ---------------- per-row phase helpers (verbatim R6 math) ----------------

__device__ __forceinline__ void stage_enc(const float* __restrict__ encp, float* s_enc, int tid)
{
  for (int idx = tid; idx < N_ * 32; idx += 256) {
    int row = idx >> 5, q = idx & 31;
    float4 v = *(const float4*)(encp + ((long long)row) * H_ + q * 4);
    float* d = s_enc + row * 132 + q * 4;
    d[0] = v.x; d[1] = v.y; d[2] = v.z; d[3] = v.w;
  }
}

__device__ __forceinline__ void build_regs(
    const float* s_enc, const float* __restrict__ Wv,
    const float* __restrict__ Wk, const float* __restrict__ Wc,
    float* vreg, float* kreg, float* preg,
    int lane, int wave, int an, int aj, int bj, int bh)
{
#pragma unroll
  for (int q = 0; q < 51; ++q) vreg[q] = 0.f;
  {
    const int base = bh * 51;
    for (int i4 = 0; i4 < 32; ++i4) {
      float w0 = Wv[(i4 * 4 + 0) * H_ + bj];
      float w1 = Wv[(i4 * 4 + 1) * H_ + bj];
      float w2 = Wv[(i4 * 4 + 2) * H_ + bj];
      float w3 = Wv[(i4 * 4 + 3) * H_ + bj];
#pragma unroll
      for (int nl = 0; nl < 51; ++nl) {
        if (base + nl < N_) {
          float4 e = *(const float4*)(s_enc + (base + nl) * 132 + i4 * 4);
          vreg[nl] += e.x * w0 + e.y * w1 + e.z * w2 + e.w * w3;
        }
      }
    }
  }
#pragma unroll
  for (int q = 0; q < 64; ++q) kreg[q] = 0.f;
  {
    const int n0 = lane;
    const int n1c = (lane < 37) ? 64 + lane : 0;
    for (int i = 0; i < 128; ++i) {
      float e0 = s_enc[n0 * 132 + i];
      float e1 = s_enc[n1c * 132 + i];
      const float4* wk0 = (const float4*)(Wk + i * H_ + wave * 16);
      const float4* wk1 = (const float4*)(Wk + i * H_ + (wave + 4) * 16);
#pragma unroll
      for (int q = 0; q < 4; ++q) {
        float4 a = wk0[q];
        kreg[q * 4 + 0] += e0 * a.x; kreg[q * 4 + 1] += e0 * a.y;
        kreg[q * 4 + 2] += e0 * a.z; kreg[q * 4 + 3] += e0 * a.w;
        kreg[32 + q * 4 + 0] += e1 * a.x; kreg[32 + q * 4 + 1] += e1 * a.y;
        kreg[32 + q * 4 + 2] += e1 * a.z; kreg[32 + q * 4 + 3] += e1 * a.w;
        float4 c = wk1[q];
        kreg[16 + q * 4 + 0] += e0 * c.x; kreg[16 + q * 4 + 1] += e0 * c.y;
        kreg[16 + q * 4 + 2] += e0 * c.z; kreg[16 + q * 4 + 3] += e0 * c.w;
        kreg[48 + q * 4 + 0] += e1 * c.x; kreg[48 + q * 4 + 1] += e1 * c.y;
        kreg[48 + q * 4 + 2] += e1 * c.z; kreg[48 + q * 4 + 3] += e1 * c.w;
      }
    }
  }
#pragma unroll
  for (int q = 0; q < 64; ++q) preg[q] = 0.f;
  if (an < N_) {
    for (int i = 0; i < 128; ++i) {
      float e = s_enc[an * 132 + i];
      const float4* wc = (const float4*)(Wc + i * H_ + aj * 64);
#pragma unroll
      for (int q = 0; q < 16; ++q) {
        float4 c = wc[q];
        preg[q * 4 + 0] += e * c.x; preg[q * 4 + 1] += e * c.y;
        preg[q * 4 + 2] += e * c.z; preg[q * 4 + 3] += e * c.w;
      }
    }
  }
}

// fused Q-build + compat + softmax (per-wave, no block barrier)
__device__ __forceinline__ void compat_sm(
    long long b, int lane, int wave, int amaxU, float capU,
    unsigned long long msklo, unsigned long long mskhi,
    const float* kreg, const float* __restrict__ encW,
    float qp_cur, float wcq, int dq,
    float* s_qsr, float* s_scr)
{
  if (lane < 32) {
    float ev = encW[(b * N_ + (long long)amaxU) * H_ + dq];  // L2-resident row
    s_qsr[wave * 32 + lane] = ev + capU * wcq + qp_cur;
  }
  asm volatile("s_waitcnt lgkmcnt(0)" ::: "memory");
  const float4* q0 = (const float4*)(s_qsr + wave * 32);
  const float4* q1 = (const float4*)(s_qsr + wave * 32 + 16);
  float c00 = 0.f, c01 = 0.f, c10 = 0.f, c11 = 0.f;
#pragma unroll
  for (int q = 0; q < 4; ++q) {
    float4 qq = q0[q];
    c00 += qq.x * kreg[q * 4 + 0] + qq.y * kreg[q * 4 + 1]
         + qq.z * kreg[q * 4 + 2] + qq.w * kreg[q * 4 + 3];
    c10 += qq.x * kreg[32 + q * 4 + 0] + qq.y * kreg[32 + q * 4 + 1]
         + qq.z * kreg[32 + q * 4 + 2] + qq.w * kreg[32 + q * 4 + 3];
    float4 qr = q1[q];
    c01 += qr.x * kreg[16 + q * 4 + 0] + qr.y * kreg[16 + q * 4 + 1]
         + qr.z * kreg[16 + q * 4 + 2] + qr.w * kreg[16 + q * 4 + 3];
    c11 += qr.x * kreg[48 + q * 4 + 0] + qr.y * kreg[48 + q * 4 + 1]
         + qr.z * kreg[48 + q * 4 + 2] + qr.w * kreg[48 + q * 4 + 3];
  }
  bool mb0 = (msklo >> lane) & 1ull;
  bool mb1v = (lane < 37) ? ((mskhi >> lane) & 1ull) : true;
  float a0 = mb0 ? -INFINITY : 0.25f * c00;
  float a1 = mb0 ? -INFINITY : 0.25f * c01;
  float b0 = mb1v ? -INFINITY : 0.25f * c10;
  float b1 = mb1v ? -INFINITY : 0.25f * c11;

  float m0  = wave_max64(fmaxf(a0, b0));
  float m1v = wave_max64(fmaxf(a1, b1));
  float ea0 = expf(a0 - m0),  eb0 = (lane < 37) ? expf(b0 - m0)  : 0.f;
  float ea1 = expf(a1 - m1v), eb1 = (lane < 37) ? expf(b1 - m1v) : 0.f;
  float s0 = ea0 + eb0, s1 = ea1 + eb1;
#pragma unroll
  for (int off = 32; off > 0; off >>= 1) {
    s0 += __shfl_xor(s0, off);
    s1 += __shfl_xor(s1, off);
  }
  float* r0 = s_scr + wave * 104;
  float* r1 = s_scr + (wave + 4) * 104;
  r0[lane] = ea0 / s0; r1[lane] = ea1 / s1;
  if (lane < 37) { r0[64 + lane] = eb0 / s0; r1[64 + lane] = eb1 / s1; }
}

__device__ __forceinline__ void glimpse_phase(
    const float* vreg, const float* s_scr, float* s_partr, int bj, int bh)
{
  int h = bj >> 4;
  const float* srow = s_scr + h * 104;
  float acc = 0.f;
  if (bh == 0) {
#pragma unroll
    for (int q = 0; q < 12; ++q) {
      float4 sv = *(const float4*)(srow + q * 4);
      acc += sv.x * vreg[q * 4 + 0] + sv.y * vreg[q * 4 + 1]
           + sv.z * vreg[q * 4 + 2] + sv.w * vreg[q * 4 + 3];
    }
    acc += srow[48] * vreg[48] + srow[49] * vreg[49] + srow[50] * vreg[50];
  } else {
    acc += srow[51] * vreg[0];
#pragma unroll
    for (int q = 0; q < 12; ++q) {
      float4 sv = *(const float4*)(srow + 52 + q * 4);
      acc += sv.x * vreg[1 + q * 4] + sv.y * vreg[2 + q * 4]
           + sv.z * vreg[3 + q * 4] + sv.w * vreg[4 + q * 4];
    }
    acc += srow[100] * vreg[49];
  }
  s_partr[bh * 128 + bj] = acc;
}

__device__ __forceinline__ void comp2_phase(
    const float* preg, const float* s_partr, float* s_p2r, int an, int aj)
{
  if (an < N_) {
    const float4* p0 = (const float4*)(s_partr + aj * 64);
    const float4* p1 = (const float4*)(s_partr + 128 + aj * 64);
    float c = 0.f;
#pragma unroll
    for (int q = 0; q < 16; ++q) {
      float4 g0 = p0[q], g1 = p1[q];
      float gx = g0.x + g1.x, gy = g0.y + g1.y, gz = g0.z + g1.z, gw = g0.w + g1.w;
      c += gx * preg[q * 4 + 0] + gy * preg[q * 4 + 1]
         + gz * preg[q * 4 + 2] + gw * preg[q * 4 + 3];
    }
    s_p2r[aj * 128 + an] = c;
  }
}

__device__ __forceinline__ void da_phase(
    long long b, int t, int tid, int lane, int wave,
    float dem0, float dem1, float cap0,
    unsigned long long& msklo, unsigned long long& mskhi,
    unsigned long long& m1lo, unsigned long long& m1hi,
    float& cap, float& logpAcc, bool& done,
    const float* s_p2r, float* s_qsr, float* s_scr,
    const float* kreg, const float* __restrict__ encW,
    float qp_nxt, float wcq, int dq,
    float* __restrict__ out)
{
  const float invSqrtH = 0.08838834764831845f;
  float l0 = -INFINITY, l1 = -INFINITY;
  bool mb0 = (msklo >> lane) & 1ull;
  if (!mb0) l0 = 10.f * tanhf((s_p2r[lane] + s_p2r[128 + lane]) * invSqrtH);
  if (lane < 37) {
    bool mb1 = (mskhi >> lane) & 1ull;
    if (!mb1) l1 = 10.f * tanhf((s_p2r[64 + lane] + s_p2r[192 + lane]) * invSqrtH);
  }
  float vmax = wave_max64(fmaxf(l0, l1));
  unsigned long long blo = __ballot(l0 == vmax);
  unsigned long long bhi = __ballot(l1 == vmax);
  int amax = blo ? (__ffsll((long long)blo) - 1)
                 : (64 + __ffsll((long long)bhi) - 1);
  float ss = wave_sum64(__expf(l0 - vmax) + __expf(l1 - vmax));  // logp path only
  logpAcc -= __logf(ss);

  float dlo = __int_as_float(__builtin_amdgcn_readlane(__float_as_int(dem0), amax & 63));
  float dhi = __int_as_float(__builtin_amdgcn_readlane(__float_as_int(dem1), amax & 63));
  float capNew = (amax == 0) ? cap0 : (cap - ((amax < 64) ? dlo : dhi));
  if (amax < 64) m1lo |= (1ull << amax); else m1hi |= (1ull << (amax - 64));
  m1lo = (m1lo & ~1ull) | (unsigned long long)(amax == 0);
  bool doneNew = ((int)__popcll(m1lo & ~1ull) + (int)__popcll(m1hi)) >= (N_ - 1);
  bool p0m = ((m1lo >> lane) & 1ull) || (dem0 > capNew);
  bool p1m = (lane < 37) ? (((m1hi >> lane) & 1ull) || (dem1 > capNew)) : true;
  unsigned long long klo = __ballot(p0m);
  unsigned long long khi = __ballot(p1m) & M37;
  if (klo == ~0ull && khi == M37) klo &= ~1ull;
  msklo = klo; mskhi = khi; cap = capNew;

  if (tid == 0) out[b * T_ + t] = (float)amax;
  if (doneNew) {
    // post-done trajectory is provably all-zeros with zero logp deltas
    for (int tt = t + 1 + tid; tt < T_; tt += 256) out[b * T_ + tt] = 0.f;
    done = true;
    return;
  }
  compat_sm(b, lane, wave, amax, capNew, msklo, mskhi, kreg, encW,
            qp_nxt, wcq, dq, s_qsr, s_scr);
}

// =====================================================================
// Decode: 256 blocks, each interleaves TWO rows (b, b+256).
// 3 barriers per PAIR-step = 1.5 per row-step; cross-row ILP fills stalls.
// =====================================================================
__global__ __attribute__((amdgpu_flat_work_group_size(256, 256), amdgpu_waves_per_eu(1, 1)))
void decode_kernel(
    const float* __restrict__ enc,
    const float* __restrict__ Wk,
    const float* __restrict__ Wv,
    const float* __restrict__ Wc,
    const float* __restrict__ encW,
    const float* __restrict__ Qpool,
    const float* __restrict__ wcap,
    const float* __restrict__ capcity,
    const float* __restrict__ demand,
    float* __restrict__ out)
{
  __shared__ __align__(16) float s_enc[N_ * 132];    // setup staging only
  __shared__ __align__(16) float s_sc[2][8 * 104];
  __shared__ __align__(16) float s_part[2][256];
  __shared__ __align__(16) float s_p2[2][256];
  __shared__ __align__(16) float s_qs[2][128];

  const long long bA = blockIdx.x;
  const long long bB = blockIdx.x + 256;
  const int tid  = threadIdx.x;
  const int lane = tid & 63;
  const int wave = tid >> 6;
  const int an = tid & 127, aj = tid >> 7;
  const int bj = tid & 127, bh = tid >> 7;

  float cap0 = capcity[0];
  float capA = capcity[bA], capB = capcity[bB];
  float dem0A = demand[bA * N_ + lane];
  float dem1A = (lane < 37) ? demand[bA * N_ + 64 + lane] : 0.f;
  float dem0B = demand[bB * N_ + lane];
  float dem1B = (lane < 37) ? demand[bB * N_ + 64 + lane] : 0.f;
  const int dq = (lane < 16) ? (wave * 16 + lane) : ((wave + 4) * 16 + (lane - 16));
  float wcq = (lane < 32) ? wcap[dq] : 0.f;
  float qpA = (lane < 32) ? Qpool[bA * H_ + dq] : 0.f;   // Qpool[t=0]
  float qpB = (lane < 32) ? Qpool[bB * H_ + dq] : 0.f;

  float vregA[51], kregA[64], pregA[64];
  float vregB[51], kregB[64], pregB[64];

  // ---- setup row A ----
  stage_enc(enc + bA * N_ * H_, s_enc, tid);
  BAR();
  build_regs(s_enc, Wv, Wk, Wc, vregA, kregA, pregA, lane, wave, an, aj, bj, bh);
  BAR();
  // ---- setup row B ----
  stage_enc(enc + bB * N_ * H_, s_enc, tid);
  BAR();
  build_regs(s_enc, Wv, Wk, Wc, vregB, kregB, pregB, lane, wave, an, aj, bj, bh);

  // ---- initial masks ----
  unsigned long long m1loA = 1ull, m1hiA = 0ull, mskloA, mskhiA;
  {
    bool p0i = (lane == 0) || (dem0A > capA);
    bool p1i = (lane < 37) ? (dem1A > capA) : true;
    mskloA = __ballot(p0i);
    mskhiA = __ballot(p1i) & M37;
    if (mskloA == ~0ull && mskhiA == M37) mskloA &= ~1ull;
  }
  unsigned long long m1loB = 1ull, m1hiB = 0ull, mskloB, mskhiB;
  {
    bool p0i = (lane == 0) || (dem0B > capB);
    bool p1i = (lane < 37) ? (dem1B > capB) : true;
    mskloB = __ballot(p0i);
    mskhiB = __ballot(p1i) & M37;
    if (mskloB == ~0ull && mskhiB == M37) mskloB &= ~1ull;
  }

  // ---- peeled step-0 compat+softmax (amax=0) ----
  compat_sm(bA, lane, wave, 0, capA, mskloA, mskhiA, kregA, encW, qpA, wcq, dq,
            s_qs[0], s_sc[0]);
  compat_sm(bB, lane, wave, 0, capB, mskloB, mskhiB, kregB, encW, qpB, wcq, dq,
            s_qs[1], s_sc[1]);
  bool doneA = false, doneB = false;
  float logpA = 0.f, logpB = 0.f;
  BAR();

  for (int t = 0; t < T_; ++t) {
    int tn = (t + 1 < T_) ? (t + 1) : t;
    float qpA_n = (!doneA && lane < 32) ? Qpool[((long long)tn * B_ + bA) * H_ + dq] : 0.f;
    float qpB_n = (!doneB && lane < 32) ? Qpool[((long long)tn * B_ + bB) * H_ + dq] : 0.f;

    if (!doneA) glimpse_phase(vregA, s_sc[0], s_part[0], bj, bh);
    if (!doneB) glimpse_phase(vregB, s_sc[1], s_part[1], bj, bh);
    BAR();

    if (!doneA) comp2_phase(pregA, s_part[0], s_p2[0], an, aj);
    if (!doneB) comp2_phase(pregB, s_part[1], s_p2[1], an, aj);
    BAR();

    if (!doneA)
      da_phase(bA, t, tid, lane, wave, dem0A, dem1A, cap0,
               mskloA, mskhiA, m1loA, m1hiA, capA, logpA, doneA,
               s_p2[0], s_qs[0], s_sc[0], kregA, encW, qpA_n, wcq, dq, out);
    if (!doneB)
      da_phase(bB, t, tid, lane, wave, dem0B, dem1B, cap0,
               mskloB, mskhiB, m1loB, m1hiB, capB, logpB, doneB,
               s_p2[1], s_qs[1], s_sc[1], kregB, encW, qpB_n, wcq, dq, out);
    if (doneA && doneB) break;
    BAR();
  }

  if (tid == 0) {
    out[(long long)B_ * T_ + bA] = logpA;
    out[(long long)B_ * T_ + bB] = logpB;
  }
}

// =====================================================================
extern "C" void kernel_launch(void* const* d_in, const int* in_sizes, int n_in,
                              void* d_out, int out_size, void* d_ws, size_t ws_size,
                              hipStream_t stream)
{
  const float* enc   = (const float*)d_in[0];
  const float* pool  = (const float*)d_in[1];
  const float* cap   = (const float*)d_in[3];
  const float* dem   = (const float*)d_in[4];
  const float* W_fc  = (const float*)d_in[7];   // 129x128
  const float* W_fc1 = (const float*)d_in[8];   // 128x128 (= F)
  const float* W_w   = (const float*)d_in[9];
  const float* W_kk  = (const float*)d_in[10];
  const float* W_vv  = (const float*)d_in[11];
  const float* W_at  = (const float*)d_in[12];
  const float* W_pk  = (const float*)d_in[13];
  float* out = (float*)d_out;
  float* ws  = (float*)d_ws;

  float* Mbuf  = ws;                               // 141 * 16384 (slots 2..140 used)
  float* Abuf  = Mbuf + 141 * 16384;               // 140 * 16384
  float* Qpl   = Abuf + 140 * 16384;               // 140 * 512 * 128
  float* encW  = Qpl + 140 * 512 * 128;            // 512 * 101 * 128
  float* Wfw   = encW + 512 * 101 * 128;           // 16384
  float* Wc    = Wfw + 16384;                      // 16384
  float* wcapb = Wc + 16384;                       // 128

  stage_a<<<13, 256, 0, stream>>>(W_fc, W_w, W_pk, W_at, W_fc1, Wfw, Wc, wcapb, Mbuf);
  stage_b<<<1624, 256, 0, stream>>>(W_fc1, enc, Wfw, Mbuf, encW);
  chainL<<<16, 256, 0, stream>>>(W_fc1, Mbuf, 4);
  chainL<<<32, 256, 0, stream>>>(W_fc1, Mbuf, 8);
  chainL<<<64, 256, 0, stream>>>(W_fc1, Mbuf, 16);
  chainL<<<128, 256, 0, stream>>>(W_fc1, Mbuf, 32);
  chainL<<<256, 256, 0, stream>>>(W_fc1, Mbuf, 64);
  stage_n8<<<556, 256, 0, stream>>>(W_fc1, W_w, Mbuf, Abuf);
  stage_n9<<<2084, 256, 0, stream>>>(W_w, pool, Mbuf, Abuf, Qpl);
  stage_n10<<<208, 256, 0, stream>>>(pool, Abuf, Qpl);
  decode_kernel<<<256, 256, 0, stream>>>(enc, W_kk, W_vv, Wc, encW, Qpl, wcapb, cap, dem, out);
}

// Round 8
// 1045.683 us; speedup vs baseline: 1.4158x; 1.4158x over previous
//
#include <hip/hip_runtime.h>
#include <math.h>

#define B_ 512
#define N_ 101
#define H_ 128
#define T_ 140
#define M37 0x1FFFFFFFFFull

// lgkm-only barrier: does NOT drain vmcnt (global prefetches stay in flight)
#define BAR() asm volatile("s_waitcnt lgkmcnt(0)\n\ts_barrier" ::: "memory")
#define LGKM0() asm volatile("s_waitcnt lgkmcnt(0)" ::: "memory")

// ---------------- DPP wave64 reductions ----------------
template <int CTRL, int RM>
__device__ __forceinline__ float dpp_max_step(float x) {
  int t = __builtin_amdgcn_update_dpp((int)0xFF800000, __float_as_int(x), CTRL, RM, 0xF, false);
  return fmaxf(x, __int_as_float(t));
}
template <int CTRL, int RM>
__device__ __forceinline__ float dpp_add_step(float x) {
  int t = __builtin_amdgcn_update_dpp(0, __float_as_int(x), CTRL, RM, 0xF, false);
  return x + __int_as_float(t);
}
__device__ __forceinline__ float wave_max64(float x) {
  x = dpp_max_step<0x111, 0xF>(x);
  x = dpp_max_step<0x112, 0xF>(x);
  x = dpp_max_step<0x114, 0xF>(x);
  x = dpp_max_step<0x118, 0xF>(x);
  x = dpp_max_step<0x142, 0xA>(x);
  x = dpp_max_step<0x143, 0xC>(x);
  return __int_as_float(__builtin_amdgcn_readlane(__float_as_int(x), 63));
}
__device__ __forceinline__ float wave_sum64(float x) {
  x = dpp_add_step<0x111, 0xF>(x);
  x = dpp_add_step<0x112, 0xF>(x);
  x = dpp_add_step<0x114, 0xF>(x);
  x = dpp_add_step<0x118, 0xF>(x);
  x = dpp_add_step<0x142, 0xA>(x);
  x = dpp_add_step<0x143, 0xC>(x);
  return __int_as_float(__builtin_amdgcn_readlane(__float_as_int(x), 63));
}

// ---------------- 128x32 GEMM tile (bit-identical to R2's gemm_tile) ----
__device__ __forceinline__ void gemm_tile_dev(
    const float* A, const float* B, float* C, int cb, int transB, int tid)
{
  int cc = cb * 32 + (tid & 7) * 4;
  int r0 = tid >> 3;
  float4 acc0 = {0,0,0,0}, acc1 = {0,0,0,0}, acc2 = {0,0,0,0}, acc3 = {0,0,0,0};
  for (int k = 0; k < 128; ++k) {
    float4 b4;
    if (!transB) {
      b4 = *(const float4*)(B + k * 128 + cc);
    } else {
      b4.x = B[(cc + 0) * 128 + k];
      b4.y = B[(cc + 1) * 128 + k];
      b4.z = B[(cc + 2) * 128 + k];
      b4.w = B[(cc + 3) * 128 + k];
    }
    float a0 = A[(r0 +  0) * 128 + k];
    float a1 = A[(r0 + 32) * 128 + k];
    float a2 = A[(r0 + 64) * 128 + k];
    float a3 = A[(r0 + 96) * 128 + k];
    acc0.x += a0 * b4.x; acc0.y += a0 * b4.y; acc0.z += a0 * b4.z; acc0.w += a0 * b4.w;
    acc1.x += a1 * b4.x; acc1.y += a1 * b4.y; acc1.z += a1 * b4.z; acc1.w += a1 * b4.w;
    acc2.x += a2 * b4.x; acc2.y += a2 * b4.y; acc2.z += a2 * b4.z; acc2.w += a2 * b4.w;
    acc3.x += a3 * b4.x; acc3.y += a3 * b4.y; acc3.z += a3 * b4.z; acc3.w += a3 * b4.w;
  }
  *(float4*)(C + (r0 +  0) * 128 + cc) = acc0;
  *(float4*)(C + (r0 + 32) * 128 + cc) = acc1;
  *(float4*)(C + (r0 + 64) * 128 + cc) = acc2;
  *(float4*)(C + (r0 + 96) * 128 + cc) = acc3;
}

// n1: Wfw(4) + Wc(4) + wcap(1) + M^2(4)
__global__ __launch_bounds__(256) void stage_a(
    const float* __restrict__ Wfc, const float* __restrict__ Ww,
    const float* __restrict__ Wpk, const float* __restrict__ Wat,
    const float* __restrict__ F,
    float* __restrict__ Wfw, float* __restrict__ Wc, float* __restrict__ wcap,
    float* __restrict__ Mbuf)
{
  int j = blockIdx.x, tid = threadIdx.x;
  if (j < 4)       gemm_tile_dev(Wfc, Ww, Wfw, j, 0, tid);
  else if (j < 8)  gemm_tile_dev(Wpk, Wat, Wc, j - 4, 1, tid);
  else if (j == 8) {
    if (tid < 128) {
      float s = 0.f;
      for (int k = 0; k < 128; ++k) s += Wfc[128 * 128 + k] * Ww[k * 128 + tid];
      wcap[tid] = s;
    }
  } else gemm_tile_dev(F, F, Mbuf + 2ll * 16384, j - 9, 0, tid);
}

// n2: chain L=2 (M^3,M^4 : 8 tiles) + encW (1616 tiles)
__global__ __launch_bounds__(256) void stage_b(
    const float* __restrict__ F, const float* __restrict__ enc,
    const float* __restrict__ Wfw, float* __restrict__ Mbuf,
    float* __restrict__ encW)
{
  int bx = blockIdx.x, tid = threadIdx.x;
  if (bx < 8) {
    int s = (bx >> 2) + 1, cb = bx & 3;
    const float* As = (s == 1) ? F : Mbuf + (long long)s * 16384;
    gemm_tile_dev(As, Mbuf + 2ll * 16384, Mbuf + (long long)(2 + s) * 16384, cb, 0, tid);
  } else {
    int jj = bx - 8, rb = jj >> 2, cb = jj & 3;
    gemm_tile_dev(enc + (long long)rb * 16384, Wfw, encW + (long long)rb * 16384, cb, 0, tid);
  }
}

// n3..n7: chain level L: M^{L+s} = M^s @ M^L, s=1..c (grid = 4c)
__global__ __launch_bounds__(256) void chainL(
    const float* __restrict__ F, float* __restrict__ Mbuf, int L)
{
  int bx = blockIdx.x, tid = threadIdx.x;
  int s = (bx >> 2) + 1, cb = bx & 3;
  const float* As = (s == 1) ? F : Mbuf + (long long)s * 16384;
  gemm_tile_dev(As, Mbuf + (long long)L * 16384, Mbuf + (long long)(L + s) * 16384, cb, 0, tid);
}

// n8: chain L=128 (48 tiles) + A_t for t=0..126 (508 tiles)
__global__ __launch_bounds__(256) void stage_n8(
    const float* __restrict__ F, const float* __restrict__ Ww,
    float* __restrict__ Mbuf, float* __restrict__ Abuf)
{
  int bx = blockIdx.x, tid = threadIdx.x;
  if (bx < 48) {
    int s = (bx >> 2) + 1, cb = bx & 3;
    const float* As = (s == 1) ? F : Mbuf + (long long)s * 16384;
    gemm_tile_dev(As, Mbuf + 128ll * 16384, Mbuf + (long long)(128 + s) * 16384, cb, 0, tid);
  } else {
    int jj = bx - 48, t = jj >> 2, cb = jj & 3;
    const float* Ms = (t == 0) ? F : Mbuf + (long long)(t + 1) * 16384;
    gemm_tile_dev(Ms, Ww, Abuf + (long long)t * 16384, cb, 0, tid);
  }
}

// n9: A_t for t=127..139 (52 tiles) + Qpool[t] for t=0..126 (2032 tiles)
__global__ __launch_bounds__(256) void stage_n9(
    const float* __restrict__ Ww, const float* __restrict__ pool,
    float* __restrict__ Mbuf, float* __restrict__ Abuf, float* __restrict__ Qpl)
{
  int bx = blockIdx.x, tid = threadIdx.x;
  if (bx < 52) {
    int t = 127 + (bx >> 2), cb = bx & 3;
    gemm_tile_dev(Mbuf + (long long)(t + 1) * 16384, Ww, Abuf + (long long)t * 16384, cb, 0, tid);
  } else {
    int jj = bx - 52, t = jj >> 4, sub = jj & 15, rb = sub >> 2, cb = sub & 3;
    gemm_tile_dev(pool + (long long)rb * 16384, Abuf + (long long)t * 16384,
                  Qpl + (long long)t * 65536 + (long long)rb * 16384, cb, 0, tid);
  }
}

// n10: Qpool[t] for t=127..139 (208 tiles)
__global__ __launch_bounds__(256) void stage_n10(
    const float* __restrict__ pool, float* __restrict__ Abuf, float* __restrict__ Qpl)
{
  int bx = blockIdx.x, tid = threadIdx.x;
  int t = 127 + (bx >> 4), sub = bx & 15, rb = sub >> 2, cb = sub & 3;
  gemm_tile_dev(pool + (long long)rb * 16384, Abuf + (long long)t * 16384,
                Qpl + (long long)t * 65536 + (long long)rb * 16384, cb, 0, tid);
}

// ---------------- fused Q-build + compat + softmax (per-wave, no block barrier)
// Values bit-identical to R6 (verified absmax 0).
__device__ __forceinline__ void compat_sm(
    int wave, int lane, int amaxU, float capU,
    unsigned long long msklo, unsigned long long mskhi,
    const float* s_buf, const float* s_wc, const float* s_qp,
    float* s_qs, const float* kreg, float* s_sc)
{
  if (lane < 32) {
    int d = (lane < 16) ? (wave * 16 + lane) : ((wave + 4) * 16 + (lane - 16));
    float qv = s_buf[amaxU * H_ + d] + capU * s_wc[d] + s_qp[d];
    s_qs[wave * 32 + lane] = qv;
  }
  LGKM0();
  const float4* q0 = (const float4*)(s_qs + wave * 32);
  const float4* q1 = (const float4*)(s_qs + wave * 32 + 16);
  float c00 = 0.f, c01 = 0.f, c10 = 0.f, c11 = 0.f;
#pragma unroll
  for (int q = 0; q < 4; ++q) {
    float4 qq = q0[q];
    c00 += qq.x * kreg[q * 4 + 0] + qq.y * kreg[q * 4 + 1]
         + qq.z * kreg[q * 4 + 2] + qq.w * kreg[q * 4 + 3];
    c10 += qq.x * kreg[32 + q * 4 + 0] + qq.y * kreg[32 + q * 4 + 1]
         + qq.z * kreg[32 + q * 4 + 2] + qq.w * kreg[32 + q * 4 + 3];
    float4 qr = q1[q];
    c01 += qr.x * kreg[16 + q * 4 + 0] + qr.y * kreg[16 + q * 4 + 1]
         + qr.z * kreg[16 + q * 4 + 2] + qr.w * kreg[16 + q * 4 + 3];
    c11 += qr.x * kreg[48 + q * 4 + 0] + qr.y * kreg[48 + q * 4 + 1]
         + qr.z * kreg[48 + q * 4 + 2] + qr.w * kreg[48 + q * 4 + 3];
  }
  bool mb0 = (msklo >> lane) & 1ull;
  bool mb1v = (lane < 37) ? ((mskhi >> lane) & 1ull) : true;
  float a0 = mb0 ? -INFINITY : 0.25f * c00;
  float a1 = mb0 ? -INFINITY : 0.25f * c01;
  float b0 = mb1v ? -INFINITY : 0.25f * c10;
  float b1 = mb1v ? -INFINITY : 0.25f * c11;

  float m0  = wave_max64(fmaxf(a0, b0));
  float m1v = wave_max64(fmaxf(a1, b1));
  float ea0 = expf(a0 - m0),  eb0 = (lane < 37) ? expf(b0 - m0)  : 0.f;
  float ea1 = expf(a1 - m1v), eb1 = (lane < 37) ? expf(b1 - m1v) : 0.f;
  float s0 = ea0 + eb0, s1 = ea1 + eb1;
#pragma unroll
  for (int off = 32; off > 0; off >>= 1) {
    s0 += __shfl_xor(s0, off);
    s1 += __shfl_xor(s1, off);
  }
  float* r0 = s_sc + wave * 104;
  float* r1 = s_sc + (wave + 4) * 104;
  r0[lane] = ea0 / s0; r1[lane] = ea1 / s1;
  if (lane < 37) { r0[64 + lane] = eb0 / s0; r1[64 + lane] = eb1 / s1; }
}

// =====================================================================
// Decode: one block per batch row; 2 barriers/step. Glimpse ownership is
// remapped so each wave reads ONLY the softmax rows it wrote (heads w, w+4)
// -> the DA/compat -> glimpse barrier is gone. All values bit-identical to R6.
// =====================================================================
__global__ __attribute__((amdgpu_flat_work_group_size(256, 256), amdgpu_waves_per_eu(2, 2)))
void decode_kernel(
    const float* __restrict__ enc,
    const float* __restrict__ Wk,
    const float* __restrict__ Wv,
    const float* __restrict__ Wc,
    const float* __restrict__ encW,
    const float* __restrict__ Qpool,
    const float* __restrict__ wcap,
    const float* __restrict__ capcity,
    const float* __restrict__ demand,
    float* __restrict__ out)
{
  __shared__ __align__(16) float s_buf[N_ * 132];  // enc (pad 132) -> encW (stride 128)
  __shared__ __align__(16) float s_sc[8 * 104];
  __shared__ __align__(16) float s_part[256];
  __shared__ __align__(16) float s_p2[256];
  __shared__ __align__(16) float s_qs[128];        // per-wave Q scratch (4 x 32)
  __shared__ __align__(16) float s_wc[128];
  __shared__ __align__(16) float s_qp[128];

  const int b    = blockIdx.x;
  const int tid  = threadIdx.x;
  const int lane = tid & 63;
  const int wave = tid >> 6;
  const int an = tid & 127, aj = tid >> 7;   // role A (comp2): n row, dim half
  // glimpse ownership remap: wave-local heads {wave, wave+4}
  const int bh2 = (lane >> 4) & 1;                                   // n half
  const int bj2 = (wave + ((lane >= 32) ? 4 : 0)) * 16 + (lane & 15); // out dim
  const float invSqrtH = 0.08838834764831845f;

  float cap  = capcity[b];
  float cap0 = capcity[0];
  float dem0 = demand[(long long)b * N_ + lane];
  float dem1 = (lane < 37) ? demand[(long long)b * N_ + 64 + lane] : 0.f;
  float wcr  = (tid < 128) ? wcap[tid] : 0.f;
  float qp0  = (tid < 128) ? Qpool[(long long)b * H_ + tid] : 0.f;

  // ---- stage enc[b] into LDS (pad 132) ----
  for (int idx = tid; idx < N_ * 32; idx += 256) {
    int row = idx >> 5, q = idx & 31;
    float4 v = *(const float4*)(enc + ((long long)b * N_ + row) * H_ + q * 4);
    float* d = s_buf + row * 132 + q * 4;
    d[0] = v.x; d[1] = v.y; d[2] = v.z; d[3] = v.w;
  }
  BAR();

  // ---- V column slices (remapped ownership): vreg[nl] = V[bh2*51+nl][bj2] ----
  float vreg[51];
#pragma unroll
  for (int q = 0; q < 51; ++q) vreg[q] = 0.f;
  {
    const int base = bh2 * 51;
    for (int i4 = 0; i4 < 32; ++i4) {
      float w0 = Wv[(i4 * 4 + 0) * H_ + bj2];
      float w1 = Wv[(i4 * 4 + 1) * H_ + bj2];
      float w2 = Wv[(i4 * 4 + 2) * H_ + bj2];
      float w3 = Wv[(i4 * 4 + 3) * H_ + bj2];
#pragma unroll
      for (int nl = 0; nl < 51; ++nl) {
        if (base + nl < N_) {
          float4 e = *(const float4*)(s_buf + (base + nl) * 132 + i4 * 4);
          vreg[nl] += e.x * w0 + e.y * w1 + e.z * w2 + e.w * w3;
        }
      }
    }
  }

  // ---- K rows, per-wave layout (as R6) ----
  float kreg[64];
#pragma unroll
  for (int q = 0; q < 64; ++q) kreg[q] = 0.f;
  {
    const int n0 = lane;
    const int n1c = (lane < 37) ? 64 + lane : 0;
    for (int i = 0; i < 128; ++i) {
      float e0 = s_buf[n0 * 132 + i];
      float e1 = s_buf[n1c * 132 + i];
      const float4* wk0 = (const float4*)(Wk + i * H_ + wave * 16);
      const float4* wk1 = (const float4*)(Wk + i * H_ + (wave + 4) * 16);
#pragma unroll
      for (int q = 0; q < 4; ++q) {
        float4 a = wk0[q];
        kreg[q * 4 + 0] += e0 * a.x; kreg[q * 4 + 1] += e0 * a.y;
        kreg[q * 4 + 2] += e0 * a.z; kreg[q * 4 + 3] += e0 * a.w;
        kreg[32 + q * 4 + 0] += e1 * a.x; kreg[32 + q * 4 + 1] += e1 * a.y;
        kreg[32 + q * 4 + 2] += e1 * a.z; kreg[32 + q * 4 + 3] += e1 * a.w;
        float4 c = wk1[q];
        kreg[16 + q * 4 + 0] += e0 * c.x; kreg[16 + q * 4 + 1] += e0 * c.y;
        kreg[16 + q * 4 + 2] += e0 * c.z; kreg[16 + q * 4 + 3] += e0 * c.w;
        kreg[48 + q * 4 + 0] += e1 * c.x; kreg[48 + q * 4 + 1] += e1 * c.y;
        kreg[48 + q * 4 + 2] += e1 * c.z; kreg[48 + q * 4 + 3] += e1 * c.w;
      }
    }
  }

  // ---- P rows (role A): preg = Kp2[an][aj*64 .. +64] ----
  float preg[64];
#pragma unroll
  for (int q = 0; q < 64; ++q) preg[q] = 0.f;
  if (an < N_) {
    for (int i = 0; i < 128; ++i) {
      float e = s_buf[an * 132 + i];
      const float4* wc = (const float4*)(Wc + i * H_ + aj * 64);
#pragma unroll
      for (int q = 0; q < 16; ++q) {
        float4 c = wc[q];
        preg[q * 4 + 0] += e * c.x; preg[q * 4 + 1] += e * c.y;
        preg[q * 4 + 2] += e * c.z; preg[q * 4 + 3] += e * c.w;
      }
    }
  }
  BAR();

  // ---- overwrite s_buf with encW (stride 128); stage s_wc / s_qp ----
  for (int idx = tid; idx < N_ * 32; idx += 256) {
    int row = idx >> 5, q = idx & 31;
    float4 v = *(const float4*)(encW + ((long long)b * N_ + row) * H_ + q * 4);
    float* d = s_buf + row * 128 + q * 4;
    d[0] = v.x; d[1] = v.y; d[2] = v.z; d[3] = v.w;
  }
  if (tid < 128) { s_wc[tid] = wcr; s_qp[tid] = qp0; }
  BAR();

  // ---- initial mask + peeled step-0 compat+softmax (amax=0, cap=initial) ----
  unsigned long long m1lo = 1ull, m1hi = 0ull;
  unsigned long long msklo, mskhi;
  {
    bool p0i = (lane == 0) || (dem0 > cap);
    bool p1i = (lane < 37) ? (dem1 > cap) : true;
    msklo = __ballot(p0i);
    mskhi = __ballot(p1i) & M37;
    if (msklo == ~0ull && mskhi == M37) msklo &= ~1ull;
  }
  float logpAcc = 0.f;
  compat_sm(wave, lane, 0, cap, msklo, mskhi, s_buf, s_wc, s_qp, s_qs, kreg, s_sc);
  // no barrier: glimpse below reads only this wave's s_sc rows

  for (int t = 0; t < T_; ++t) {
    int tn = (t + 1 < T_) ? (t + 1) : t;
    float qn = (tid < 128) ? Qpool[((long long)tn * B_ + b) * H_ + tid] : 0.f;

    // ---- B: glimpse partial (wave-local heads) ----
    {
      LGKM0();  // own-wave s_sc writes from compat_sm
      const float* srow = s_sc + (bj2 >> 4) * 104;
      float acc = 0.f;
      if (bh2 == 0) {
#pragma unroll
        for (int q = 0; q < 12; ++q) {
          float4 sv = *(const float4*)(srow + q * 4);
          acc += sv.x * vreg[q * 4 + 0] + sv.y * vreg[q * 4 + 1]
               + sv.z * vreg[q * 4 + 2] + sv.w * vreg[q * 4 + 3];
        }
        acc += srow[48] * vreg[48] + srow[49] * vreg[49] + srow[50] * vreg[50];
      } else {
        acc += srow[51] * vreg[0];
#pragma unroll
        for (int q = 0; q < 12; ++q) {
          float4 sv = *(const float4*)(srow + 52 + q * 4);
          acc += sv.x * vreg[1 + q * 4] + sv.y * vreg[2 + q * 4]
               + sv.z * vreg[3 + q * 4] + sv.w * vreg[4 + q * 4];
        }
        acc += srow[100] * vreg[49];
      }
      s_part[bh2 * 128 + bj2] = acc;
    }
    BAR();

    // ---- C: comp2 partial (role A) + s_qp refresh ----
    if (an < N_) {
      const float4* p0 = (const float4*)(s_part + aj * 64);
      const float4* p1 = (const float4*)(s_part + 128 + aj * 64);
      float c = 0.f;
#pragma unroll
      for (int q = 0; q < 16; ++q) {
        float4 g0 = p0[q], g1 = p1[q];
        float gx = g0.x + g1.x, gy = g0.y + g1.y, gz = g0.z + g1.z, gw = g0.w + g1.w;
        c += gx * preg[q * 4 + 0] + gy * preg[q * 4 + 1]
           + gz * preg[q * 4 + 2] + gw * preg[q * 4 + 3];
      }
      s_p2[aj * 128 + an] = c;
    }
    if (tid < 128) s_qp[tid] = qn;
    BAR();

    // ---- DA: logits, argmax, lse, state, then fused next-step compat ----
    {
      float l0 = -INFINITY, l1 = -INFINITY;
      bool mb0 = (msklo >> lane) & 1ull;
      if (!mb0) l0 = 10.f * tanhf((s_p2[lane] + s_p2[128 + lane]) * invSqrtH);
      if (lane < 37) {
        bool mb1 = (mskhi >> lane) & 1ull;
        if (!mb1) l1 = 10.f * tanhf((s_p2[64 + lane] + s_p2[192 + lane]) * invSqrtH);
      }
      float vmax = wave_max64(fmaxf(l0, l1));
      unsigned long long blo = __ballot(l0 == vmax);
      unsigned long long bhi = __ballot(l1 == vmax);
      int amax = blo ? (__ffsll((long long)blo) - 1)
                     : (64 + __ffsll((long long)bhi) - 1);
      float ss = wave_sum64(__expf(l0 - vmax) + __expf(l1 - vmax));  // logp path only
      logpAcc -= __logf(ss);

      float dlo = __int_as_float(__builtin_amdgcn_readlane(__float_as_int(dem0), amax & 63));
      float dhi = __int_as_float(__builtin_amdgcn_readlane(__float_as_int(dem1), amax & 63));
      float capNew = (amax == 0) ? cap0 : (cap - ((amax < 64) ? dlo : dhi));
      if (amax < 64) m1lo |= (1ull << amax); else m1hi |= (1ull << (amax - 64));
      m1lo = (m1lo & ~1ull) | (unsigned long long)(amax == 0);
      bool doneNew = ((int)__popcll(m1lo & ~1ull) + (int)__popcll(m1hi)) >= (N_ - 1);
      bool p0m = ((m1lo >> lane) & 1ull) || (dem0 > capNew);
      bool p1m = (lane < 37) ? (((m1hi >> lane) & 1ull) || (dem1 > capNew)) : true;
      unsigned long long klo = __ballot(p0m);
      unsigned long long khi = __ballot(p1m) & M37;
      if (klo == ~0ull && khi == M37) klo &= ~1ull;
      msklo = klo; mskhi = khi; cap = capNew;

      if (tid == 0) out[(long long)b * T_ + t] = (float)amax;
      if (doneNew) {
        // post-done trajectory is provably all-zeros with zero logp deltas
        for (int tt = t + 1 + tid; tt < T_; tt += 256)
          out[(long long)b * T_ + tt] = 0.f;
        break;
      }
      if (t + 1 < T_)
        compat_sm(wave, lane, amax, capNew, msklo, mskhi,
                  s_buf, s_wc, s_qp, s_qs, kreg, s_sc);
      // no barrier: next glimpse reads only this wave's s_sc rows
    }
  }

  if (tid == 0) out[(long long)B_ * T_ + b] = logpAcc;
}

// =====================================================================
extern "C" void kernel_launch(void* const* d_in, const int* in_sizes, int n_in,
                              void* d_out, int out_size, void* d_ws, size_t ws_size,
                              hipStream_t stream)
{
  const float* enc   = (const float*)d_in[0];
  const float* pool  = (const float*)d_in[1];
  const float* cap   = (const float*)d_in[3];
  const float* dem   = (const float*)d_in[4];
  const float* W_fc  = (const float*)d_in[7];   // 129x128
  const float* W_fc1 = (const float*)d_in[8];   // 128x128 (= F)
  const float* W_w   = (const float*)d_in[9];
  const float* W_kk  = (const float*)d_in[10];
  const float* W_vv  = (const float*)d_in[11];
  const float* W_at  = (const float*)d_in[12];
  const float* W_pk  = (const float*)d_in[13];
  float* out = (float*)d_out;
  float* ws  = (float*)d_ws;

  float* Mbuf  = ws;                               // 141 * 16384 (slots 2..140 used)
  float* Abuf  = Mbuf + 141 * 16384;               // 140 * 16384
  float* Qpl   = Abuf + 140 * 16384;               // 140 * 512 * 128
  float* encW  = Qpl + 140 * 512 * 128;            // 512 * 101 * 128
  float* Wfw   = encW + 512 * 101 * 128;           // 16384
  float* Wc    = Wfw + 16384;                      // 16384
  float* wcapb = Wc + 16384;                       // 128

  stage_a<<<13, 256, 0, stream>>>(W_fc, W_w, W_pk, W_at, W_fc1, Wfw, Wc, wcapb, Mbuf);
  stage_b<<<1624, 256, 0, stream>>>(W_fc1, enc, Wfw, Mbuf, encW);
  chainL<<<16, 256, 0, stream>>>(W_fc1, Mbuf, 4);
  chainL<<<32, 256, 0, stream>>>(W_fc1, Mbuf, 8);
  chainL<<<64, 256, 0, stream>>>(W_fc1, Mbuf, 16);
  chainL<<<128, 256, 0, stream>>>(W_fc1, Mbuf, 32);
  chainL<<<256, 256, 0, stream>>>(W_fc1, Mbuf, 64);
  stage_n8<<<556, 256, 0, stream>>>(W_fc1, W_w, Mbuf, Abuf);
  stage_n9<<<2084, 256, 0, stream>>>(W_w, pool, Mbuf, Abuf, Qpl);
  stage_n10<<<208, 256, 0, stream>>>(pool, Abuf, Qpl);
  decode_kernel<<<512, 256, 0, stream>>>(enc, W_kk, W_vv, Wc, encW, Qpl, wcapb, cap, dem, out);
}